// Round 4
// baseline (502.693 us; speedup 1.0000x reference)
//
#include <hip/hip_runtime.h>
#include <math.h>

#define N_NODES 50000
#define F 64
#define OUTF 32
#define NX2 (N_NODES * 32)          // packed bf16-pair count of x
#define NPREP (16384 + 2048 + 128 + 32)

#define B1 32        // histW blocks
#define HRANGE 12500 // nodes per histW pass (50 KB LDS f32)
#define B2 256       // count/fill blocks
#define RNG 200      // nodes per propagate range (50 KB LDS f32)
#define R_RANGES 250 // 250 * 200 = 50000

typedef __bf16 v8bf __attribute__((ext_vector_type(8)));
typedef float v4f __attribute__((ext_vector_type(4)));

static __device__ __forceinline__ unsigned short f2bf(float f) {
    union { float f; unsigned u; } v; v.f = f;
    unsigned r = v.u + 0x7FFFu + ((v.u >> 16) & 1u);   // round-to-nearest-even
    return (unsigned short)(r >> 16);
}
static __device__ __forceinline__ float bf2f(unsigned short h) {
    union { unsigned u; float f; } v; v.u = ((unsigned)h) << 16;
    return v.f;
}

// ---------------- pre: cast x->bf16 pairs + weight prep ----------------
__global__ void pre_kernel(const float2* __restrict__ x2, unsigned int* __restrict__ xb2,
                           const float* __restrict__ Wxz0, const float* __restrict__ Wxz1,
                           const float* __restrict__ Wxh0, const float* __restrict__ Wxh1,
                           const float* __restrict__ Wlin,
                           const float* __restrict__ bxz, const float* __restrict__ bhz,
                           const float* __restrict__ bxh, const float* __restrict__ bhh,
                           const float* __restrict__ blin,
                           unsigned short* __restrict__ Bt, unsigned short* __restrict__ Wlt,
                           float* __restrict__ bzc, float* __restrict__ blc) {
    int i = blockIdx.x * 256 + threadIdx.x;
    if (i < NX2) {
        float2 v = x2[i];
        xb2[i] = (unsigned)f2bf(v.x) | ((unsigned)f2bf(v.y) << 16);
    } else {
        int idx = i - NX2;
        if (idx < 16384) {
            int k = idx & 127, n = idx >> 7;
            float v;
            if (k < 64) v = (n < 64) ? Wxz0[k * 64 + n] : Wxh0[k * 64 + (n - 64)];
            else        v = (n < 64) ? Wxz1[(k - 64) * 64 + n] : Wxh1[(k - 64) * 64 + (n - 64)];
            Bt[n * 128 + k] = f2bf(v);
        } else if (idx < 16384 + 2048) {
            int j = idx - 16384; int k = j & 63, n = j >> 6;
            Wlt[n * 64 + k] = f2bf(Wlin[k * 32 + n]);
        } else if (idx < 16384 + 2048 + 128) {
            int j = idx - 16384 - 2048;
            bzc[j] = (j < 64) ? (bxz[j] + bhz[j]) : (bxh[j - 64] + bhh[j - 64]);
        } else if (idx < NPREP) {
            int j = idx - 16384 - 2048 - 128;
            blc[j] = blin[j];
        }
    }
}

// ---------------- histW: LDS-privatized weighted degree histogram (by src) ----------------
__launch_bounds__(1024)
__global__ void histw_kernel(const int* __restrict__ src, const float* __restrict__ ew,
                             float* __restrict__ partW, int E) {
    __shared__ float sdeg[HRANGE];   // 50 KB
    int b = blockIdx.x, tid = threadIdx.x;
    int epb = (E + B1 - 1) / B1;
    int lo = b * epb, hi = min(lo + epb, E);
    for (int pass = 0; pass < 4; ++pass) {
        int base = pass * HRANGE;
        for (int i = tid; i < HRANGE; i += 1024) sdeg[i] = 0.f;
        __syncthreads();
        for (int e = lo + tid; e < hi; e += 1024) {
            int s = src[e];
            unsigned ls = (unsigned)(s - base);
            if (ls < HRANGE) atomicAdd(&sdeg[ls], ew[e]);
        }
        __syncthreads();
        for (int i = tid; i < HRANGE; i += 1024)
            partW[(size_t)b * N_NODES + base + i] = sdeg[i];
        __syncthreads();
    }
}

// ---------------- reduceW: sum partials -> dinv ----------------
__global__ void reducew_kernel(const float* __restrict__ partW, float* __restrict__ dinv) {
    int i = blockIdx.x * 256 + threadIdx.x;
    if (i >= N_NODES) return;
    float s = 0.f;
    #pragma unroll
    for (int b = 0; b < B1; ++b) s += partW[(size_t)b * N_NODES + i];
    dinv[i] = s > 0.f ? rsqrtf(s) : 0.f;
}

// ---------------- countB: per-(block, range) dst counts ----------------
__launch_bounds__(256)
__global__ void countb_kernel(const int* __restrict__ dst, unsigned* __restrict__ cntBR, int E) {
    __shared__ unsigned sc[256];
    int b = blockIdx.x, tid = threadIdx.x;
    sc[tid] = 0u;
    __syncthreads();
    int epb = (E + B2 - 1) / B2;
    int lo = b * epb, hi = min(lo + epb, E);
    for (int e = lo + tid; e < hi; e += 256) {
        unsigned d = (unsigned)dst[e];
        if (d < N_NODES) atomicAdd(&sc[d / RNG], 1u);
    }
    __syncthreads();
    cntBR[b * 256 + tid] = sc[tid];
}

// ---------------- scanBR: column scan over blocks + range scan -> absolute bases ----------------
__launch_bounds__(256)
__global__ void scanbr_kernel(unsigned* __restrict__ cntBR,
                              unsigned* __restrict__ rstart, unsigned* __restrict__ rcnt) {
    __shared__ unsigned t[256];
    int r = threadIdx.x;
    unsigned acc = 0;
    for (int b = 0; b < B2; ++b) {
        unsigned v = cntBR[b * 256 + r];
        cntBR[b * 256 + r] = acc;     // within-range running base
        acc += v;
    }
    t[r] = acc;
    __syncthreads();
    for (int d = 1; d < 256; d <<= 1) {
        unsigned y = (r >= d) ? t[r - d] : 0u;
        __syncthreads();
        t[r] += y;
        __syncthreads();
    }
    unsigned start = t[r] - acc;      // exclusive scan over ranges
    rstart[r] = start;
    rcnt[r] = acc;
    for (int b = 0; b < B2; ++b) cntBR[b * 256 + r] += start;
}

// ---------------- fill: bucket edges by dst-range, LDS cursors (no global atomics) ----------------
__launch_bounds__(256)
__global__ void fill_kernel(const int* __restrict__ src, const int* __restrict__ dst,
                            const float* __restrict__ ew, const float* __restrict__ dinv,
                            const unsigned* __restrict__ baseBR, uint2* __restrict__ bucket, int E) {
    __shared__ unsigned curs[256];
    int b = blockIdx.x, tid = threadIdx.x;
    curs[tid] = baseBR[b * 256 + tid];
    __syncthreads();
    int epb = (E + B2 - 1) / B2;
    int lo = b * epb, hi = min(lo + epb, E);
    for (int e = lo + tid; e < hi; e += 256) {
        int s = src[e];
        unsigned d = (unsigned)dst[e];
        if ((unsigned)s >= N_NODES || d >= N_NODES) continue;
        float pc = -dinv[s] * ew[e];          // dinv[dst] factored out to propagate epilogue
        unsigned r = d / RNG;
        unsigned slot = atomicAdd(&curs[r], 1u);   // LDS atomic: fast, CU-local
        bucket[slot] = make_uint2((unsigned)s | ((d - r * RNG) << 16), __float_as_uint(pc));
    }
}

// ---------------- propagate: per-range LDS f32 accumulation (no global atomics) ----------------
__launch_bounds__(512)
__global__ void prop_kernel(const unsigned* __restrict__ rstart, const unsigned* __restrict__ rcnt,
                            const uint2* __restrict__ bucket, const unsigned* __restrict__ xb2,
                            const float* __restrict__ dinv, unsigned* __restrict__ Pb2) {
    __shared__ float sacc[RNG * 64];   // 50 KB
    int r = blockIdx.x, tid = threadIdx.x;
    for (int i = tid; i < RNG * 64; i += 512) sacc[i] = 0.f;
    __syncthreads();
    unsigned beg = rstart[r], cnt = rcnt[r];
    int hw = tid >> 5, l32 = tid & 31;   // 16 half-waves; one edge per half-wave
    for (unsigned i = hw; i < cnt; i += 16) {
        uint2 rec = bucket[beg + i];
        unsigned s = rec.x & 0xFFFFu, dl = rec.x >> 16;
        float c = __uint_as_float(rec.y);
        unsigned xv = xb2[(size_t)s * 32 + l32];
        float fx = bf2f((unsigned short)(xv & 0xFFFFu));
        float fy = bf2f((unsigned short)(xv >> 16));
        atomicAdd(&sacc[dl * 64 + l32 * 2], c * fx);
        atomicAdd(&sacc[dl * 64 + l32 * 2 + 1], c * fy);
    }
    __syncthreads();
    int nbase = r * RNG;
    for (int i = tid; i < RNG * 32; i += 512) {
        int dl = i >> 5, f2 = i & 31;
        int node = nbase + dl;
        if (node < N_NODES) {
            float dv = dinv[node];
            float a = sacc[dl * 64 + f2 * 2] * dv;
            float bv = sacc[dl * 64 + f2 * 2 + 1] * dv;
            Pb2[(size_t)node * 32 + f2] = (unsigned)f2bf(a) | ((unsigned)f2bf(bv) << 16);
        }
    }
}

// ---------------- fused dense (MFMA): gates GEMM + GRU + linear + L2-normalize ----------------
__launch_bounds__(256, 3)
__global__ void dense_kernel(const unsigned short* __restrict__ xb, const unsigned short* __restrict__ Pb,
                             const unsigned short* __restrict__ Bt, const unsigned short* __restrict__ Wlt,
                             const float* __restrict__ bzc, const float* __restrict__ blc,
                             float* __restrict__ out) {
    __shared__ unsigned short Bs[128 * 136];
    __shared__ unsigned short Wls[32 * 80];
    __shared__ unsigned short Hs[4][16 * 80];
    __shared__ float bzs[128], bls[32];

    int tid = threadIdx.x;
    for (int c = tid; c < 4096; c += 256) {
        int n = c >> 5; int k4 = (c & 31) * 4;
        *(uint2*)&Bs[n * 136 + k4] = *(const uint2*)&Bt[n * 128 + k4];
    }
    for (int c = tid; c < 512; c += 256) {
        int n = c >> 4; int k4 = (c & 15) * 4;
        *(uint2*)&Wls[n * 80 + k4] = *(const uint2*)&Wlt[n * 64 + k4];
    }
    if (tid < 128) bzs[tid] = bzc[tid];
    if (tid < 32) bls[tid] = blc[tid];
    __syncthreads();

    int wv = tid >> 6, lane = tid & 63;
    int nl = lane & 15, q = lane >> 4;
    int rowbase = blockIdx.x * 64 + wv * 16;

    int arow = rowbase + nl; if (arow >= N_NODES) arow = N_NODES - 1;
    v4f acc[8];
    #pragma unroll
    for (int i = 0; i < 8; ++i) acc[i] = (v4f)(0.f);

    #pragma unroll
    for (int kk = 0; kk < 4; ++kk) {
        int k0 = kk * 32 + q * 8;
        const unsigned short* ap = (kk < 2) ? (xb + (size_t)arow * 64 + k0)
                                            : (Pb + (size_t)arow * 64 + (k0 - 64));
        v8bf a = *(const v8bf*)ap;
        #pragma unroll
        for (int tn = 0; tn < 8; ++tn) {
            v8bf b = *(const v8bf*)&Bs[(tn * 16 + nl) * 136 + kk * 32 + q * 8];
            acc[tn] = __builtin_amdgcn_mfma_f32_16x16x32_bf16(a, b, acc[tn], 0, 0, 0);
        }
    }

    #pragma unroll
    for (int tn = 0; tn < 4; ++tn) {
        int n = tn * 16 + nl;
        float bz = bzs[n], bh = bzs[64 + n];
        #pragma unroll
        for (int r = 0; r < 4; ++r) {
            float z = acc[tn][r] + bz;
            float h = acc[tn + 4][r] + bh;
            float sg = 1.f / (1.f + __expf(-z));
            float th = 1.f - 2.f / (__expf(2.f * h) + 1.f);
            int m = q * 4 + r;
            Hs[wv][m * 80 + n] = f2bf((1.f - sg) * th);
        }
    }

    v4f acc2[2];
    acc2[0] = (v4f)(0.f); acc2[1] = (v4f)(0.f);
    #pragma unroll
    for (int kk = 0; kk < 2; ++kk) {
        v8bf a = *(const v8bf*)&Hs[wv][nl * 80 + kk * 32 + q * 8];
        #pragma unroll
        for (int tn = 0; tn < 2; ++tn) {
            v8bf b = *(const v8bf*)&Wls[(tn * 16 + nl) * 80 + kk * 32 + q * 8];
            acc2[tn] = __builtin_amdgcn_mfma_f32_16x16x32_bf16(a, b, acc2[tn], 0, 0, 0);
        }
    }

    float o0[4], o1[4];
    #pragma unroll
    for (int r = 0; r < 4; ++r) {
        o0[r] = acc2[0][r] + bls[nl];
        o1[r] = acc2[1][r] + bls[16 + nl];
    }
    #pragma unroll
    for (int r = 0; r < 4; ++r) {
        float ss = o0[r] * o0[r] + o1[r] * o1[r];
        ss += __shfl_xor(ss, 1);
        ss += __shfl_xor(ss, 2);
        ss += __shfl_xor(ss, 4);
        ss += __shfl_xor(ss, 8);
        float dn = fmaxf(sqrtf(ss), 1e-12f);
        int node = rowbase + q * 4 + r;
        if (node < N_NODES) {
            out[node * 32 + nl] = o0[r] / dn;
            out[node * 32 + 16 + nl] = o1[r] / dn;
        }
    }
}

extern "C" void kernel_launch(void* const* d_in, const int* in_sizes, int n_in,
                              void* d_out, int out_size, void* d_ws, size_t ws_size,
                              hipStream_t stream) {
    const float* x    = (const float*)d_in[0];
    const int*   ei   = (const int*)d_in[1];
    const float* ew   = (const float*)d_in[2];
    const float* Wxz0 = (const float*)d_in[3];
    const float* Wxz1 = (const float*)d_in[4];
    const float* bxz  = (const float*)d_in[5];
    const float* bhz  = (const float*)d_in[8];
    const float* Wxh0 = (const float*)d_in[15];
    const float* Wxh1 = (const float*)d_in[16];
    const float* bxh  = (const float*)d_in[17];
    const float* bhh  = (const float*)d_in[20];
    const float* Wlin = (const float*)d_in[21];
    const float* blin = (const float*)d_in[22];
    float* out = (float*)d_out;

    int E = in_sizes[2];
    const int* src = ei;
    const int* dst = ei + E;

    // workspace layout (bytes), no zero-init needed anywhere:
    // [0, 200000)              dinv      (f32)
    // [200000, 6600000)        xb        (bf16 N*64)
    // [6600000, 13000000)      Pb        (bf16 N*64)
    // [13000000, +max(B1*N*4, E*8))  partW (f32 B1 x N), overlaid by bucket (uint2 E) after reduceW
    // then: cntBR (u32 B2*256) | rstart (u32 256) | rcnt (u32 256) | Bt | Wlt | bzc | blc
    char* base = (char*)d_ws;
    float*          dinv   = (float*)(base + 0);
    unsigned short* xb     = (unsigned short*)(base + 200000);
    unsigned short* Pb     = (unsigned short*)(base + 6600000);
    size_t xsz = (size_t)B1 * N_NODES * 4;
    size_t bsz = (size_t)E * 8;
    size_t Xsz = xsz > bsz ? xsz : bsz;
    float*          partW  = (float*)(base + 13000000);
    uint2*          bucket = (uint2*)(base + 13000000);
    char* p = base + 13000000 + Xsz;
    unsigned*       cntBR  = (unsigned*)p;            p += (size_t)B2 * 256 * 4;
    unsigned*       rstart = (unsigned*)p;            p += 1024;
    unsigned*       rcnt   = (unsigned*)p;            p += 1024;
    unsigned short* Bt     = (unsigned short*)p;      p += 128 * 128 * 2;
    unsigned short* Wlt    = (unsigned short*)p;      p += 32 * 64 * 2;
    float*          bzc    = (float*)p;               p += 128 * 4;
    float*          blc    = (float*)p;

    pre_kernel<<<(NX2 + NPREP + 255) / 256, 256, 0, stream>>>(
        (const float2*)x, (unsigned int*)xb,
        Wxz0, Wxz1, Wxh0, Wxh1, Wlin, bxz, bhz, bxh, bhh, blin,
        Bt, Wlt, bzc, blc);

    histw_kernel<<<B1, 1024, 0, stream>>>(src, ew, partW, E);
    reducew_kernel<<<(N_NODES + 255) / 256, 256, 0, stream>>>(partW, dinv);
    countb_kernel<<<B2, 256, 0, stream>>>(dst, cntBR, E);
    scanbr_kernel<<<1, 256, 0, stream>>>(cntBR, rstart, rcnt);
    fill_kernel<<<B2, 256, 0, stream>>>(src, dst, ew, dinv, cntBR, bucket, E);
    prop_kernel<<<R_RANGES, 512, 0, stream>>>(rstart, rcnt, bucket, (const unsigned*)xb, dinv, (unsigned*)Pb);
    dense_kernel<<<(N_NODES + 63) / 64, 256, 0, stream>>>(xb, Pb, Bt, Wlt, bzc, blc, out);
}

// Round 5
// 255.476 us; speedup vs baseline: 1.9677x; 1.9677x over previous
//
#include <hip/hip_runtime.h>
#include <math.h>

#define N_NODES 50000
#define F 64
#define OUTF 32
#define NX4 (N_NODES * 16)          // float4 count of x
#define NPREP (16384 + 2048 + 128 + 32)

#define B1H 64       // histW blocks
#define HR 25000     // nodes per histW pass (100 KB LDS f32)

typedef __bf16 v8bf __attribute__((ext_vector_type(8)));
typedef float v4f __attribute__((ext_vector_type(4)));

static __device__ __forceinline__ unsigned short f2bf(float f) {
    union { float f; unsigned u; } v; v.f = f;
    unsigned r = v.u + 0x7FFFu + ((v.u >> 16) & 1u);   // round-to-nearest-even
    return (unsigned short)(r >> 16);
}
static __device__ __forceinline__ float bf2f(unsigned short h) {
    union { unsigned u; float f; } v; v.u = ((unsigned)h) << 16;
    return v.f;
}

// ---------------- pre: cast x->bf16 pairs (float4-vectorized) + weight prep ----------------
__global__ void pre_kernel(const float4* __restrict__ x4, uint2* __restrict__ xb4,
                           const float* __restrict__ Wxz0, const float* __restrict__ Wxz1,
                           const float* __restrict__ Wxh0, const float* __restrict__ Wxh1,
                           const float* __restrict__ Wlin,
                           const float* __restrict__ bxz, const float* __restrict__ bhz,
                           const float* __restrict__ bxh, const float* __restrict__ bhh,
                           const float* __restrict__ blin,
                           unsigned short* __restrict__ Bt, unsigned short* __restrict__ Wlt,
                           float* __restrict__ bzc, float* __restrict__ blc) {
    int i = blockIdx.x * 256 + threadIdx.x;
    if (i < NX4) {
        float4 v = x4[i];
        uint2 o;
        o.x = (unsigned)f2bf(v.x) | ((unsigned)f2bf(v.y) << 16);
        o.y = (unsigned)f2bf(v.z) | ((unsigned)f2bf(v.w) << 16);
        xb4[i] = o;
    } else {
        int idx = i - NX4;
        if (idx < 16384) {
            int k = idx & 127, n = idx >> 7;
            float v;
            if (k < 64) v = (n < 64) ? Wxz0[k * 64 + n] : Wxh0[k * 64 + (n - 64)];
            else        v = (n < 64) ? Wxz1[(k - 64) * 64 + n] : Wxh1[(k - 64) * 64 + (n - 64)];
            Bt[n * 128 + k] = f2bf(v);
        } else if (idx < 16384 + 2048) {
            int j = idx - 16384; int k = j & 63, n = j >> 6;
            Wlt[n * 64 + k] = f2bf(Wlin[k * 32 + n]);
        } else if (idx < 16384 + 2048 + 128) {
            int j = idx - 16384 - 2048;
            bzc[j] = (j < 64) ? (bxz[j] + bhz[j]) : (bxh[j - 64] + bhh[j - 64]);
        } else if (idx < NPREP) {
            int j = idx - 16384 - 2048 - 128;
            blc[j] = blin[j];
        }
    }
}

// ---------------- histW: LDS-privatized weighted degree histogram (by src), partials ----------------
__launch_bounds__(1024)
__global__ void histw_kernel(const int* __restrict__ src, const float* __restrict__ ew,
                             float* __restrict__ partW, int E) {
    __shared__ float sdeg[HR];   // 100 KB
    int b = blockIdx.x, tid = threadIdx.x;
    int epb = (E + B1H - 1) / B1H;
    int lo = b * epb, hi = min(lo + epb, E);
    #pragma unroll
    for (int pass = 0; pass < 2; ++pass) {
        int base = pass * HR;
        for (int i = tid; i < HR; i += 1024) sdeg[i] = 0.f;
        __syncthreads();
        for (int e = lo + tid; e < hi; e += 1024) {
            int s = src[e];
            unsigned ls = (unsigned)(s - base);
            if (ls < HR) atomicAdd(&sdeg[ls], ew[e]);
        }
        __syncthreads();
        for (int i = tid; i < HR; i += 1024)
            partW[(size_t)b * N_NODES + base + i] = sdeg[i];
        __syncthreads();
    }
}

// ---------------- reduceW: sum partials -> dinv ----------------
__global__ void reducew_kernel(const float* __restrict__ partW, float* __restrict__ dinv) {
    int i = blockIdx.x * 256 + threadIdx.x;
    if (i >= N_NODES) return;
    float s = 0.f;
    #pragma unroll
    for (int b = 0; b < B1H; ++b) s += partW[(size_t)b * N_NODES + i];
    dinv[i] = s > 0.f ? rsqrtf(s) : 0.f;
}

// ---------------- scatter: Pb[d,:] += coef * xb[s,:]  (coalesced packed bf16 atomics) ----------------
// 2 edges per wave; 32 lanes/edge; each lane handles 2 features via pk_add_bf16
__global__ void scatter_kernel(const int* __restrict__ src, const int* __restrict__ dst,
                               const float* __restrict__ w, const float* __restrict__ dinv,
                               const unsigned int* __restrict__ xb2, unsigned int* __restrict__ Pb2,
                               int E) {
    int t = blockIdx.x * 256 + threadIdx.x;
    int e = t >> 5;
    if (e >= E) return;
    int lane = t & 31;
    int s = src[e], d = dst[e];
    if ((unsigned)s >= N_NODES || (unsigned)d >= N_NODES) return;
    float coef = -dinv[s] * w[e] * dinv[d];
    unsigned xv = xb2[(size_t)s * 32 + lane];
    unsigned short lo = f2bf(coef * bf2f((unsigned short)(xv & 0xFFFFu)));
    unsigned short hi = f2bf(coef * bf2f((unsigned short)(xv >> 16)));
    unsigned packed = (unsigned)lo | ((unsigned)hi << 16);
    unsigned int* addr = Pb2 + (size_t)d * 32 + lane;
    asm volatile("global_atomic_pk_add_bf16 %0, %1, off" :: "v"(addr), "v"(packed) : "memory");
}

// ---------------- fused dense (MFMA, persistent): gates GEMM + GRU + linear + L2-normalize ----------------
__launch_bounds__(256, 2)
__global__ void dense_kernel(const unsigned short* __restrict__ xb, const unsigned short* __restrict__ Pb,
                             const unsigned short* __restrict__ Bt, const unsigned short* __restrict__ Wlt,
                             const float* __restrict__ bzc, const float* __restrict__ blc,
                             float* __restrict__ out) {
    __shared__ unsigned short Bs[128 * 136];
    __shared__ unsigned short Wls[32 * 80];
    __shared__ unsigned short Hs[4][16 * 80];
    __shared__ float bzs[128], bls[32];

    int tid = threadIdx.x;
    for (int c = tid; c < 4096; c += 256) {
        int n = c >> 5; int k4 = (c & 31) * 4;
        *(uint2*)&Bs[n * 136 + k4] = *(const uint2*)&Bt[n * 128 + k4];
    }
    for (int c = tid; c < 512; c += 256) {
        int n = c >> 4; int k4 = (c & 15) * 4;
        *(uint2*)&Wls[n * 80 + k4] = *(const uint2*)&Wlt[n * 64 + k4];
    }
    if (tid < 128) bzs[tid] = bzc[tid];
    if (tid < 32) bls[tid] = blc[tid];
    __syncthreads();

    int wv = tid >> 6, lane = tid & 63;
    int nl = lane & 15, q = lane >> 4;
    int ngroups = (N_NODES + 63) / 64;

    for (int g = blockIdx.x; g < ngroups; g += gridDim.x) {
        int rowbase = g * 64 + wv * 16;
        int arow = rowbase + nl; if (arow >= N_NODES) arow = N_NODES - 1;

        v4f acc[8];
        #pragma unroll
        for (int i = 0; i < 8; ++i) acc[i] = (v4f)(0.f);

        #pragma unroll
        for (int kk = 0; kk < 4; ++kk) {
            int k0 = kk * 32 + q * 8;
            const unsigned short* ap = (kk < 2) ? (xb + (size_t)arow * 64 + k0)
                                                : (Pb + (size_t)arow * 64 + (k0 - 64));
            v8bf a = *(const v8bf*)ap;
            #pragma unroll
            for (int tn = 0; tn < 8; ++tn) {
                v8bf b = *(const v8bf*)&Bs[(tn * 16 + nl) * 136 + kk * 32 + q * 8];
                acc[tn] = __builtin_amdgcn_mfma_f32_16x16x32_bf16(a, b, acc[tn], 0, 0, 0);
            }
        }

        #pragma unroll
        for (int tn = 0; tn < 4; ++tn) {
            int n = tn * 16 + nl;
            float bz = bzs[n], bh = bzs[64 + n];
            #pragma unroll
            for (int r = 0; r < 4; ++r) {
                float z = acc[tn][r] + bz;
                float h = acc[tn + 4][r] + bh;
                float sg = 1.f / (1.f + __expf(-z));
                float th = 1.f - 2.f / (__expf(2.f * h) + 1.f);
                int m = q * 4 + r;
                Hs[wv][m * 80 + n] = f2bf((1.f - sg) * th);
            }
        }
        // Hs[wv] is wave-private; compiler's lgkmcnt ordering covers write->read

        v4f acc2[2];
        acc2[0] = (v4f)(0.f); acc2[1] = (v4f)(0.f);
        #pragma unroll
        for (int kk = 0; kk < 2; ++kk) {
            v8bf a = *(const v8bf*)&Hs[wv][nl * 80 + kk * 32 + q * 8];
            #pragma unroll
            for (int tn = 0; tn < 2; ++tn) {
                v8bf b = *(const v8bf*)&Wls[(tn * 16 + nl) * 80 + kk * 32 + q * 8];
                acc2[tn] = __builtin_amdgcn_mfma_f32_16x16x32_bf16(a, b, acc2[tn], 0, 0, 0);
            }
        }

        float o0[4], o1[4];
        #pragma unroll
        for (int r = 0; r < 4; ++r) {
            o0[r] = acc2[0][r] + bls[nl];
            o1[r] = acc2[1][r] + bls[16 + nl];
        }
        #pragma unroll
        for (int r = 0; r < 4; ++r) {
            float ss = o0[r] * o0[r] + o1[r] * o1[r];
            ss += __shfl_xor(ss, 1);
            ss += __shfl_xor(ss, 2);
            ss += __shfl_xor(ss, 4);
            ss += __shfl_xor(ss, 8);
            float dn = fmaxf(sqrtf(ss), 1e-12f);
            int node = rowbase + q * 4 + r;
            if (node < N_NODES) {
                out[node * 32 + nl] = o0[r] / dn;
                out[node * 32 + 16 + nl] = o1[r] / dn;
            }
        }
    }
}

extern "C" void kernel_launch(void* const* d_in, const int* in_sizes, int n_in,
                              void* d_out, int out_size, void* d_ws, size_t ws_size,
                              hipStream_t stream) {
    const float* x    = (const float*)d_in[0];
    const int*   ei   = (const int*)d_in[1];
    const float* ew   = (const float*)d_in[2];
    const float* Wxz0 = (const float*)d_in[3];
    const float* Wxz1 = (const float*)d_in[4];
    const float* bxz  = (const float*)d_in[5];
    const float* bhz  = (const float*)d_in[8];
    const float* Wxh0 = (const float*)d_in[15];
    const float* Wxh1 = (const float*)d_in[16];
    const float* bxh  = (const float*)d_in[17];
    const float* bhh  = (const float*)d_in[20];
    const float* Wlin = (const float*)d_in[21];
    const float* blin = (const float*)d_in[22];
    float* out = (float*)d_out;

    int E = in_sizes[2];
    const int* src = ei;
    const int* dst = ei + E;

    // workspace layout (bytes):
    // [0, 200000)              dinv   (f32)
    // [200000, 6600000)        xb     (bf16 N*64)
    // [6600000, 13000000)      Pb     (bf16 N*64, memset AFTER reducew)
    // [6600000, 19400000)      partW  (f32 64 x N) -- overlays Pb; dead before Pb memset
    // [19400000, ...)          Bt | Wlt | bzc | blc
    char* base = (char*)d_ws;
    float*          dinv   = (float*)(base + 0);
    unsigned short* xb     = (unsigned short*)(base + 200000);
    unsigned short* Pb     = (unsigned short*)(base + 6600000);
    float*          partW  = (float*)(base + 6600000);
    char* p = base + 19400000;
    unsigned short* Bt     = (unsigned short*)p;      p += 128 * 128 * 2;
    unsigned short* Wlt    = (unsigned short*)p;      p += 32 * 64 * 2;
    float*          bzc    = (float*)p;               p += 128 * 4;
    float*          blc    = (float*)p;

    pre_kernel<<<(NX4 + NPREP + 255) / 256, 256, 0, stream>>>(
        (const float4*)x, (uint2*)xb,
        Wxz0, Wxz1, Wxh0, Wxh1, Wlin, bxz, bhz, bxh, bhh, blin,
        Bt, Wlt, bzc, blc);

    histw_kernel<<<B1H, 1024, 0, stream>>>(src, ew, partW, E);
    reducew_kernel<<<(N_NODES + 255) / 256, 256, 0, stream>>>(partW, dinv);

    // zero Pb only now (partW overlay is dead)
    hipMemsetAsync(Pb, 0, (size_t)N_NODES * F * 2, stream);

    scatter_kernel<<<(E * 32 + 255) / 256, 256, 0, stream>>>(src, dst, ew, dinv,
                                                             (const unsigned int*)xb, (unsigned int*)Pb, E);
    dense_kernel<<<512, 256, 0, stream>>>(xb, Pb, Bt, Wlt, bzc, blc, out);
}